// Round 2
// baseline (435.294 us; speedup 1.0000x reference)
//
#include <hip/hip_runtime.h>

#define BATCH 4
#define HH 1024
#define WW 1024

// ---------------- downsample 1024 -> 256 (bilinear, antialias=False) ----------
// out coord i samples input at 4i+1.5 -> avg of pixels {4i+1,4i+2} x {4j+1,4j+2}
__global__ __launch_bounds__(256) void downsample_k(const float* __restrict__ img,
                                                    float* __restrict__ low) {
  int idx = blockIdx.x * 256 + threadIdx.x;     // B*3*256*256 = 786432
  int x = idx & 255;
  int y = (idx >> 8) & 255;
  int bc = idx >> 16;                            // b*3 + c
  const float* p = img + (size_t)bc * HH * WW;
  int iy = 4 * y + 1, ix = 4 * x + 1;
  float v = 0.25f * (p[iy * WW + ix] + p[iy * WW + ix + 1] +
                     p[(iy + 1) * WW + ix] + p[(iy + 1) * WW + ix + 1]);
  low[idx] = v;
}

// ---------------- 3x3 stride-2 conv, pad 1, relu ------------------------------
template <int CI, int CO, int HI>
__global__ __launch_bounds__(256) void conv_s2_k(const float* __restrict__ in,
                                                 const float* __restrict__ wgt,
                                                 const float* __restrict__ bias,
                                                 float* __restrict__ out) {
  const int WI = HI;
  const int HO = HI / 2, WO = HI / 2;
  int idx = blockIdx.x * 256 + threadIdx.x;
  if (idx >= BATCH * CO * HO * WO) return;
  int x = idx % WO;
  int t = idx / WO;
  int y = t % HO; t /= HO;
  int o = t % CO;
  int b = t / CO;
  float acc = bias[o];
  int iy0 = 2 * y - 1, ix0 = 2 * x - 1;
  for (int ci = 0; ci < CI; ++ci) {
    const float* ip = in + (size_t)(b * CI + ci) * HI * WI;
    const float* wp = wgt + (o * CI + ci) * 9;
#pragma unroll
    for (int ky = 0; ky < 3; ++ky) {
      int iy = iy0 + ky;
      if (iy < 0 || iy >= HI) continue;
#pragma unroll
      for (int kx = 0; kx < 3; ++kx) {
        int ix = ix0 + kx;
        if (ix < 0 || ix >= WI) continue;
        acc += wp[ky * 3 + kx] * ip[iy * WI + ix];
      }
    }
  }
  out[idx] = fmaxf(acc, 0.0f);
}

// ---------------- splat = pw(x3, spw) + spb + val  (NO relu) ------------------
__global__ __launch_bounds__(256) void splat_k(const float* __restrict__ x3,
                                               const float* __restrict__ spw,
                                               const float* __restrict__ spb,
                                               const float* __restrict__ val,
                                               float* __restrict__ out) {
  int idx = blockIdx.x * 256 + threadIdx.x;  // B*64*256 = 65536
  int p = idx & 255;
  int o = (idx >> 8) & 63;
  int b = idx >> 14;
  float acc = spb[o] + val[b];
  const float* w = spw + o * 64;
  const float* xb = x3 + ((size_t)b * 64) * 256 + p;
#pragma unroll 8
  for (int c = 0; c < 64; ++c) acc += w[c] * xb[c * 256];
  out[idx] = acc;
}

// ---------------- pointwise conv + relu ---------------------------------------
template <int CI, int CO>
__global__ __launch_bounds__(256) void pw_relu_k(const float* __restrict__ in,
                                                 const float* __restrict__ wgt,
                                                 const float* __restrict__ bias,
                                                 float* __restrict__ out) {
  int idx = blockIdx.x * 256 + threadIdx.x;
  if (idx >= BATCH * CO * 256) return;
  int p = idx & 255;
  int o = (idx >> 8) % CO;
  int b = idx / (CO * 256);
  float acc = bias[o];
  const float* w = wgt + o * CI;
  const float* xb = in + ((size_t)b * CI) * 256 + p;
#pragma unroll 8
  for (int c = 0; c < CI; ++c) acc += w[c] * xb[c * 256];
  out[idx] = fmaxf(acc, 0.0f);
}

// ---------------- global path: strided pw conv + relu + 2x2 mean pool ---------
// splat[:, :, ::2, ::2] -> relu(pw cw) -> (B,4,8,8) -> avgpool2 -> (B,4,4,4) -> cvec(B,64)
__global__ __launch_bounds__(256) void cpool_k(const float* __restrict__ splat,
                                               const float* __restrict__ cw,
                                               const float* __restrict__ cb,
                                               float* __restrict__ cvec) {
  int t = threadIdx.x;  // 256 total, 1 block
  int b = t >> 6;
  int r = t & 63;                 // ch*16 + py*4 + px
  int ch = r >> 4;
  int py = (r >> 2) & 3;
  int px = r & 3;
  float sum = 0.f;
  for (int dy = 0; dy < 2; ++dy)
    for (int dx = 0; dx < 2; ++dx) {
      int yy = py * 2 + dy, xx = px * 2 + dx;  // position in 8x8
      int p = (yy * 2) * 16 + xx * 2;          // ::2,::2 of 16x16
      float acc = cb[ch];
      const float* w = cw + ch * 64;
      const float* xb = splat + ((size_t)b * 64) * 256 + p;
#pragma unroll 8
      for (int c = 0; c < 64; ++c) acc += w[c] * xb[c * 256];
      sum += fmaxf(acc, 0.f);
    }
  cvec[t] = sum * 0.25f;
}

// ---------------- two FC layers (B,64)->(B,64)->(B,64), relu ------------------
__global__ __launch_bounds__(256) void fc_k(const float* __restrict__ cvec,
                                            const float* __restrict__ fw1,
                                            const float* __restrict__ fb1,
                                            const float* __restrict__ fw2,
                                            const float* __restrict__ fb2,
                                            float* __restrict__ fc2o) {
  __shared__ float sc[256];
  __shared__ float h1[256];
  int t = threadIdx.x;
  sc[t] = cvec[t];
  __syncthreads();
  int b = t >> 6, o = t & 63;
  float acc = fb1[o];
#pragma unroll 8
  for (int k = 0; k < 64; ++k) acc += fw1[o * 64 + k] * sc[b * 64 + k];
  h1[t] = fmaxf(acc, 0.f);
  __syncthreads();
  acc = fb2[o];
#pragma unroll 8
  for (int k = 0; k < 64; ++k) acc += fw2[o * 64 + k] * h1[b * 64 + k];
  fc2o[t] = fmaxf(acc, 0.f);
}

// ---------------- fused = relu(loc3 + c), coeff = pw(fused, gw), scatter grid -
// grid_t layout: [b][z(8)][gy*16+gx][cc(12)]  (cc contiguous -> float4-able)
__global__ __launch_bounds__(256) void coeff_k(const float* __restrict__ loc3,
                                               const float* __restrict__ fc2o,
                                               const float* __restrict__ gw,
                                               const float* __restrict__ gb,
                                               float* __restrict__ gridt) {
  int idx = blockIdx.x * 256 + threadIdx.x;  // B*96*256 = 98304
  int p = idx & 255;
  int o = (idx >> 8) % 96;
  int b = idx / (96 * 256);
  float acc = gb[o];
  const float* w = gw + o * 64;
  const float* xb = loc3 + ((size_t)b * 64) * 256 + p;
  const float* cb = fc2o + b * 64;
#pragma unroll 8
  for (int c = 0; c < 64; ++c) {
    float f = xb[c * 256] + cb[c];
    acc += w[c] * fmaxf(f, 0.f);
  }
  int l = o / 12, cc = o % 12;
  gridt[(size_t)(((b * 8 + l) << 8) + p) * 12 + cc] = acc;
}

// ---------------- guide + bilateral slice + affine apply (fused) --------------
__global__ __launch_bounds__(256) void slice_k(
    const float* __restrict__ img, const float* __restrict__ gridt,
    const float* __restrict__ ccm_w, const float* __restrict__ ccm_b,
    const float* __restrict__ shifts, const float* __restrict__ slopes,
    const float* __restrict__ prw, const float* __restrict__ prb,
    float* __restrict__ out) {
  int gidx = blockIdx.x * 256 + threadIdx.x;  // B*H*W/4 groups
  int b = gidx >> 18;
  int pp = (gidx & 0x3FFFF) << 2;  // pixel index within batch plane
  int h = pp >> 10;
  int w0 = pp & 1023;

  const float* ib = img + (size_t)b * 3 * HH * WW;
  float4 R4 = *(const float4*)(ib + pp);
  float4 G4 = *(const float4*)(ib + HH * WW + pp);
  float4 B4 = *(const float4*)(ib + 2 * HH * WW + pp);
  float r_[4] = {R4.x, R4.y, R4.z, R4.w};
  float g_[4] = {G4.x, G4.y, G4.z, G4.w};
  float b_[4] = {B4.x, B4.y, B4.z, B4.w};

  float m0 = ccm_w[0], m1 = ccm_w[1], m2 = ccm_w[2];
  float m3 = ccm_w[3], m4 = ccm_w[4], m5 = ccm_w[5];
  float m6 = ccm_w[6], m7 = ccm_w[7], m8 = ccm_w[8];
  float c0 = ccm_b[0], c1 = ccm_b[1], c2 = ccm_b[2];
  float p0 = prw[0], p1 = prw[1], p2 = prw[2], pb = prb[0];

  float cy = (h + 0.5f) * 0.015625f - 0.5f;
  float y0f = floorf(cy);
  float wy = cy - y0f;
  int y0 = (int)y0f;
  int yi0 = min(max(y0, 0), 15), yi1 = min(max(y0 + 1, 0), 15);

  float ro[4], go[4], bo[4];
#pragma unroll
  for (int j = 0; j < 4; ++j) {
    float r = r_[j], g = g_[j], bl = b_[j];
    // guide: ccm -> piecewise-linear curve -> projection -> clip
    float v0 = c0 + m0 * r + m1 * g + m2 * bl;
    float v1 = c1 + m3 * r + m4 * g + m5 * bl;
    float v2 = c2 + m6 * r + m7 * g + m8 * bl;
    float t0 = 0.f, t1 = 0.f, t2 = 0.f;
#pragma unroll
    for (int k = 0; k < 16; ++k) {
      t0 += slopes[k] * fmaxf(v0 - shifts[k], 0.f);
      t1 += slopes[16 + k] * fmaxf(v1 - shifts[16 + k], 0.f);
      t2 += slopes[32 + k] * fmaxf(v2 - shifts[32 + k], 0.f);
    }
    float gg = pb + p0 * t0 + p1 * t1 + p2 * t2;
    float guide = fminf(fmaxf(gg, 0.f), 1.f);

    int w = w0 + j;
    float cx = (w + 0.5f) * 0.015625f - 0.5f;
    float x0f = floorf(cx);
    float wx = cx - x0f;
    int x0i = (int)x0f;
    int xi0 = min(max(x0i, 0), 15), xi1 = min(max(x0i + 1, 0), 15);

    float cz = guide * 8.0f - 0.5f;
    float z0f = floorf(cz);
    float wz = cz - z0f;
    int z0i = (int)z0f;
    int zi0 = min(max(z0i, 0), 7), zi1 = min(max(z0i + 1, 0), 7);

    float acc[12];
#pragma unroll
    for (int k = 0; k < 12; ++k) acc[k] = 0.f;

#pragma unroll
    for (int dz = 0; dz < 2; ++dz) {
      int zi = dz ? zi1 : zi0;
      float wzz = dz ? wz : 1.f - wz;
#pragma unroll
      for (int dy = 0; dy < 2; ++dy) {
        int yi = dy ? yi1 : yi0;
        float wyy = dy ? wy : 1.f - wy;
#pragma unroll
        for (int dx = 0; dx < 2; ++dx) {
          int xi = dx ? xi1 : xi0;
          float wxx = dx ? wx : 1.f - wx;
          float wgt = wzz * wyy * wxx;
          const float* gp = gridt + (size_t)(((b * 8 + zi) << 8) + (yi << 4) + xi) * 12;
          float4 a0 = *(const float4*)gp;
          float4 a1 = *(const float4*)(gp + 4);
          float4 a2 = *(const float4*)(gp + 8);
          acc[0] += wgt * a0.x;  acc[1] += wgt * a0.y;
          acc[2] += wgt * a0.z;  acc[3] += wgt * a0.w;
          acc[4] += wgt * a1.x;  acc[5] += wgt * a1.y;
          acc[6] += wgt * a1.z;  acc[7] += wgt * a1.w;
          acc[8] += wgt * a2.x;  acc[9] += wgt * a2.y;
          acc[10] += wgt * a2.z; acc[11] += wgt * a2.w;
        }
      }
    }
    ro[j] = acc[0] * r + acc[1] * g + acc[2] * bl + acc[3];
    go[j] = acc[4] * r + acc[5] * g + acc[6] * bl + acc[7];
    bo[j] = acc[8] * r + acc[9] * g + acc[10] * bl + acc[11];
  }
  float* ob = out + (size_t)b * 3 * HH * WW;
  *(float4*)(ob + pp) = make_float4(ro[0], ro[1], ro[2], ro[3]);
  *(float4*)(ob + HH * WW + pp) = make_float4(go[0], go[1], go[2], go[3]);
  *(float4*)(ob + 2 * HH * WW + pp) = make_float4(bo[0], bo[1], bo[2], bo[3]);
}

extern "C" void kernel_launch(void* const* d_in, const int* in_sizes, int n_in,
                              void* d_out, int out_size, void* d_ws, size_t ws_size,
                              hipStream_t stream) {
  const float* image = (const float*)d_in[0];
  const float* val   = (const float*)d_in[1];
  const float* sw0 = (const float*)d_in[2];  const float* sb0 = (const float*)d_in[3];
  const float* sw1 = (const float*)d_in[4];  const float* sb1 = (const float*)d_in[5];
  const float* sw2 = (const float*)d_in[6];  const float* sb2 = (const float*)d_in[7];
  const float* sw3 = (const float*)d_in[8];  const float* sb3 = (const float*)d_in[9];
  const float* spw = (const float*)d_in[10]; const float* spb = (const float*)d_in[11];
  const float* lw1 = (const float*)d_in[12]; const float* lb1 = (const float*)d_in[13];
  const float* lw2 = (const float*)d_in[14]; const float* lb2 = (const float*)d_in[15];
  const float* lw3 = (const float*)d_in[16]; const float* lb3 = (const float*)d_in[17];
  const float* cw  = (const float*)d_in[18]; const float* cb  = (const float*)d_in[19];
  const float* fw1 = (const float*)d_in[20]; const float* fb1 = (const float*)d_in[21];
  const float* fw2 = (const float*)d_in[22]; const float* fb2 = (const float*)d_in[23];
  const float* gw  = (const float*)d_in[24]; const float* gb  = (const float*)d_in[25];
  const float* ccm_w = (const float*)d_in[26]; const float* ccm_b = (const float*)d_in[27];
  const float* shifts = (const float*)d_in[28]; const float* slopes = (const float*)d_in[29];
  const float* prw = (const float*)d_in[30]; const float* prb = (const float*)d_in[31];
  float* out = (float*)d_out;

  float* ws    = (float*)d_ws;
  float* low   = ws;                  // 786432
  float* x0    = low + 786432;        // 524288
  float* x1    = x0 + 524288;         // 262144
  float* x2    = x1 + 262144;         // 131072
  float* x3    = x2 + 131072;         // 65536
  float* splat = x3 + 65536;          // 65536
  float* loc1  = splat + 65536;       // 131072
  float* loc2  = loc1 + 131072;       // 131072
  float* loc3  = loc2 + 131072;       // 65536
  float* cvec  = loc3 + 65536;        // 256
  float* fc2o  = cvec + 256;          // 256
  float* gridt = fc2o + 256;          // 98304

  downsample_k<<<3072, 256, 0, stream>>>(image, low);
  conv_s2_k<3, 8, 256><<<2048, 256, 0, stream>>>(low, sw0, sb0, x0);
  conv_s2_k<8, 16, 128><<<1024, 256, 0, stream>>>(x0, sw1, sb1, x1);
  conv_s2_k<16, 32, 64><<<512, 256, 0, stream>>>(x1, sw2, sb2, x2);
  conv_s2_k<32, 64, 32><<<256, 256, 0, stream>>>(x2, sw3, sb3, x3);
  splat_k<<<256, 256, 0, stream>>>(x3, spw, spb, val, splat);
  pw_relu_k<64, 128><<<512, 256, 0, stream>>>(splat, lw1, lb1, loc1);
  pw_relu_k<128, 128><<<512, 256, 0, stream>>>(loc1, lw2, lb2, loc2);
  pw_relu_k<128, 64><<<256, 256, 0, stream>>>(loc2, lw3, lb3, loc3);
  cpool_k<<<1, 256, 0, stream>>>(splat, cw, cb, cvec);
  fc_k<<<1, 256, 0, stream>>>(cvec, fw1, fb1, fw2, fb2, fc2o);
  coeff_k<<<384, 256, 0, stream>>>(loc3, fc2o, gw, gb, gridt);
  slice_k<<<4096, 256, 0, stream>>>(image, gridt, ccm_w, ccm_b, shifts, slopes,
                                    prw, prb, out);
}

// Round 3
// 339.101 us; speedup vs baseline: 1.2837x; 1.2837x over previous
//
#include <hip/hip_runtime.h>

#define BATCH 4
#define HH 1024
#define WW 1024

// ---------------- downsample 1024 -> 256 (bilinear, antialias=False) ----------
__global__ __launch_bounds__(256) void downsample_k(const float* __restrict__ img,
                                                    float* __restrict__ low) {
  int idx = blockIdx.x * 256 + threadIdx.x;     // B*3*256*256 = 786432
  int x = idx & 255;
  int y = (idx >> 8) & 255;
  int bc = idx >> 16;                            // b*3 + c
  const float* p = img + (size_t)bc * HH * WW;
  int iy = 4 * y + 1, ix = 4 * x + 1;
  float v = 0.25f * (p[iy * WW + ix] + p[iy * WW + ix + 1] +
                     p[(iy + 1) * WW + ix] + p[(iy + 1) * WW + ix + 1]);
  low[idx] = v;
}

// ---------------- 3x3 stride-2 conv, pad 1, relu ------------------------------
template <int CI, int CO, int HI>
__global__ __launch_bounds__(256) void conv_s2_k(const float* __restrict__ in,
                                                 const float* __restrict__ wgt,
                                                 const float* __restrict__ bias,
                                                 float* __restrict__ out) {
  const int WI = HI;
  const int HO = HI / 2, WO = HI / 2;
  int idx = blockIdx.x * 256 + threadIdx.x;
  if (idx >= BATCH * CO * HO * WO) return;
  int x = idx % WO;
  int t = idx / WO;
  int y = t % HO; t /= HO;
  int o = t % CO;
  int b = t / CO;
  float acc = bias[o];
  int iy0 = 2 * y - 1, ix0 = 2 * x - 1;
  for (int ci = 0; ci < CI; ++ci) {
    const float* ip = in + (size_t)(b * CI + ci) * HI * WI;
    const float* wp = wgt + (o * CI + ci) * 9;
#pragma unroll
    for (int ky = 0; ky < 3; ++ky) {
      int iy = iy0 + ky;
      if (iy < 0 || iy >= HI) continue;
#pragma unroll
      for (int kx = 0; kx < 3; ++kx) {
        int ix = ix0 + kx;
        if (ix < 0 || ix >= WI) continue;
        acc += wp[ky * 3 + kx] * ip[iy * WI + ix];
      }
    }
  }
  out[idx] = fmaxf(acc, 0.0f);
}

// ---------------- splat = pw(x3, spw) + spb + val  (NO relu) ------------------
__global__ __launch_bounds__(256) void splat_k(const float* __restrict__ x3,
                                               const float* __restrict__ spw,
                                               const float* __restrict__ spb,
                                               const float* __restrict__ val,
                                               float* __restrict__ out) {
  int idx = blockIdx.x * 256 + threadIdx.x;  // B*64*256 = 65536
  int p = idx & 255;
  int o = (idx >> 8) & 63;
  int b = idx >> 14;
  float acc = spb[o] + val[b];
  const float* w = spw + o * 64;
  const float* xb = x3 + ((size_t)b * 64) * 256 + p;
#pragma unroll 8
  for (int c = 0; c < 64; ++c) acc += w[c] * xb[c * 256];
  out[idx] = acc;
}

// ---------------- pointwise conv + relu ---------------------------------------
template <int CI, int CO>
__global__ __launch_bounds__(256) void pw_relu_k(const float* __restrict__ in,
                                                 const float* __restrict__ wgt,
                                                 const float* __restrict__ bias,
                                                 float* __restrict__ out) {
  int idx = blockIdx.x * 256 + threadIdx.x;
  if (idx >= BATCH * CO * 256) return;
  int p = idx & 255;
  int o = (idx >> 8) % CO;
  int b = idx / (CO * 256);
  float acc = bias[o];
  const float* w = wgt + o * CI;
  const float* xb = in + ((size_t)b * CI) * 256 + p;
#pragma unroll 8
  for (int c = 0; c < CI; ++c) acc += w[c] * xb[c * 256];
  out[idx] = fmaxf(acc, 0.0f);
}

// ---------------- fused global path: cpool + 2 FC layers (one block) ----------
__global__ __launch_bounds__(256) void cpfc_k(const float* __restrict__ splat,
                                              const float* __restrict__ cw,
                                              const float* __restrict__ cb,
                                              const float* __restrict__ fw1,
                                              const float* __restrict__ fb1,
                                              const float* __restrict__ fw2,
                                              const float* __restrict__ fb2,
                                              float* __restrict__ fc2o) {
  __shared__ float sc[256];
  __shared__ float h1[256];
  int t = threadIdx.x;
  int b = t >> 6;
  int r = t & 63;                 // ch*16 + py*4 + px
  int ch = r >> 4;
  int py = (r >> 2) & 3;
  int px = r & 3;
  float sum = 0.f;
  for (int dy = 0; dy < 2; ++dy)
    for (int dx = 0; dx < 2; ++dx) {
      int yy = py * 2 + dy, xx = px * 2 + dx;  // position in 8x8
      int p = (yy * 2) * 16 + xx * 2;          // ::2,::2 of 16x16
      float acc = cb[ch];
      const float* w = cw + ch * 64;
      const float* xb = splat + ((size_t)b * 64) * 256 + p;
#pragma unroll 8
      for (int c = 0; c < 64; ++c) acc += w[c] * xb[c * 256];
      sum += fmaxf(acc, 0.f);
    }
  sc[t] = sum * 0.25f;
  __syncthreads();
  int o = t & 63;
  float acc = fb1[o];
#pragma unroll 8
  for (int k = 0; k < 64; ++k) acc += fw1[o * 64 + k] * sc[b * 64 + k];
  h1[t] = fmaxf(acc, 0.f);
  __syncthreads();
  acc = fb2[o];
#pragma unroll 8
  for (int k = 0; k < 64; ++k) acc += fw2[o * 64 + k] * h1[b * 64 + k];
  fc2o[t] = fmaxf(acc, 0.f);
}

// ---------------- fused = relu(loc3 + c), coeff = pw(fused, gw), scatter grid -
// grid_t layout: [b][z(8)][gy*16+gx][cc(12)]  (cc contiguous -> float4-able)
__global__ __launch_bounds__(256) void coeff_k(const float* __restrict__ loc3,
                                               const float* __restrict__ fc2o,
                                               const float* __restrict__ gw,
                                               const float* __restrict__ gb,
                                               float* __restrict__ gridt) {
  int idx = blockIdx.x * 256 + threadIdx.x;  // B*96*256 = 98304
  int p = idx & 255;
  int o = (idx >> 8) % 96;
  int b = idx / (96 * 256);
  float acc = gb[o];
  const float* w = gw + o * 64;
  const float* xb = loc3 + ((size_t)b * 64) * 256 + p;
  const float* cvb = fc2o + b * 64;
#pragma unroll 8
  for (int c = 0; c < 64; ++c) {
    float f = xb[c * 256] + cvb[c];
    acc += w[c] * fmaxf(f, 0.f);
  }
  int l = o / 12, cc = o % 12;
  gridt[(size_t)(((b * 8 + l) << 8) + p) * 12 + cc] = acc;
}

// ---------------- guide + bilateral slice + affine apply (fused, LDS grid) ----
// One block per (batch, image row). The row's grid support = 2 y-cells x 16 x
// x 8 z x 12 coeffs = 3072 floats, staged in LDS with padded z-slice stride
// (208 floats: 16B-aligned, adjacent z offset by 16 banks -> no full-bank
// collision for z-divergent lanes).
#define ZSTRIDE 208
__global__ __launch_bounds__(256) void slice_k(
    const float* __restrict__ img, const float* __restrict__ gridt,
    const float* __restrict__ ccm_w, const float* __restrict__ ccm_b,
    const float* __restrict__ shifts, const float* __restrict__ slopes,
    const float* __restrict__ prw, const float* __restrict__ prb,
    float* __restrict__ out) {
  int blk = blockIdx.x;          // BATCH*1024
  int b = blk >> 10;
  int h = blk & 1023;
  int t = threadIdx.x;

  __shared__ float sg[16 * ZSTRIDE];  // [chunk=dy*8+z][x*12+c], 13312 B

  float cy = (h + 0.5f) * 0.015625f - 0.5f;
  float y0f = floorf(cy);
  float wy = cy - y0f;
  int y0 = (int)y0f;
  int yi0 = min(max(y0, 0), 15), yi1 = min(max(y0 + 1, 0), 15);

  // cooperative stage: 16 chunks x 48 float4 (192 floats contiguous in global)
  for (int i = t; i < 768; i += 256) {
    int chunk = i / 48;
    int e = i - chunk * 48;
    int dy = chunk >> 3;
    int z = chunk & 7;
    int yi = dy ? yi1 : yi0;
    const float4* src =
        (const float4*)(gridt + (size_t)(((b * 8 + z) << 8) + (yi << 4)) * 12);
    *((float4*)(sg + chunk * ZSTRIDE) + e) = src[e];
  }
  __syncthreads();

  int pp = (h << 10) + (t << 2);  // offset within one plane
  const float* ib = img + (size_t)b * 3 * HH * WW;
  float4 R4 = *(const float4*)(ib + pp);
  float4 G4 = *(const float4*)(ib + HH * WW + pp);
  float4 B4 = *(const float4*)(ib + 2 * HH * WW + pp);
  float r_[4] = {R4.x, R4.y, R4.z, R4.w};
  float g_[4] = {G4.x, G4.y, G4.z, G4.w};
  float b_[4] = {B4.x, B4.y, B4.z, B4.w};

  float m0 = ccm_w[0], m1 = ccm_w[1], m2 = ccm_w[2];
  float m3 = ccm_w[3], m4 = ccm_w[4], m5 = ccm_w[5];
  float m6 = ccm_w[6], m7 = ccm_w[7], m8 = ccm_w[8];
  float c0 = ccm_b[0], c1 = ccm_b[1], c2 = ccm_b[2];
  float p0 = prw[0], p1 = prw[1], p2 = prw[2], pb = prb[0];

  float ro[4], go[4], bo[4];
#pragma unroll
  for (int j = 0; j < 4; ++j) {
    float r = r_[j], g = g_[j], bl = b_[j];
    // guide: ccm -> piecewise-linear curve -> projection -> clip
    float v0 = c0 + m0 * r + m1 * g + m2 * bl;
    float v1 = c1 + m3 * r + m4 * g + m5 * bl;
    float v2 = c2 + m6 * r + m7 * g + m8 * bl;
    float t0 = 0.f, t1 = 0.f, t2 = 0.f;
#pragma unroll
    for (int k = 0; k < 16; ++k) {
      t0 += slopes[k] * fmaxf(v0 - shifts[k], 0.f);
      t1 += slopes[16 + k] * fmaxf(v1 - shifts[16 + k], 0.f);
      t2 += slopes[32 + k] * fmaxf(v2 - shifts[32 + k], 0.f);
    }
    float gg = pb + p0 * t0 + p1 * t1 + p2 * t2;
    float guide = fminf(fmaxf(gg, 0.f), 1.f);

    int w = (t << 2) + j;
    float cx = (w + 0.5f) * 0.015625f - 0.5f;
    float x0f = floorf(cx);
    float wx = cx - x0f;
    int x0i = (int)x0f;
    int xi0 = min(max(x0i, 0), 15), xi1 = min(max(x0i + 1, 0), 15);

    float cz = guide * 8.0f - 0.5f;
    float z0f = floorf(cz);
    float wz = cz - z0f;
    int z0i = (int)z0f;
    int zi0 = min(max(z0i, 0), 7), zi1 = min(max(z0i + 1, 0), 7);

    float acc[12];
#pragma unroll
    for (int k = 0; k < 12; ++k) acc[k] = 0.f;

#pragma unroll
    for (int dz = 0; dz < 2; ++dz) {
      int zi = dz ? zi1 : zi0;
      float wzz = dz ? wz : 1.f - wz;
#pragma unroll
      for (int dy = 0; dy < 2; ++dy) {
        float wyy = dy ? wy : 1.f - wy;
#pragma unroll
        for (int dx = 0; dx < 2; ++dx) {
          int xi = dx ? xi1 : xi0;
          float wxx = dx ? wx : 1.f - wx;
          float wgt = wzz * wyy * wxx;
          const float* gp = sg + (dy * 8 + zi) * ZSTRIDE + xi * 12;
          float4 a0 = *(const float4*)gp;
          float4 a1 = *(const float4*)(gp + 4);
          float4 a2 = *(const float4*)(gp + 8);
          acc[0] += wgt * a0.x;  acc[1] += wgt * a0.y;
          acc[2] += wgt * a0.z;  acc[3] += wgt * a0.w;
          acc[4] += wgt * a1.x;  acc[5] += wgt * a1.y;
          acc[6] += wgt * a1.z;  acc[7] += wgt * a1.w;
          acc[8] += wgt * a2.x;  acc[9] += wgt * a2.y;
          acc[10] += wgt * a2.z; acc[11] += wgt * a2.w;
        }
      }
    }
    ro[j] = acc[0] * r + acc[1] * g + acc[2] * bl + acc[3];
    go[j] = acc[4] * r + acc[5] * g + acc[6] * bl + acc[7];
    bo[j] = acc[8] * r + acc[9] * g + acc[10] * bl + acc[11];
  }
  float* ob = out + (size_t)b * 3 * HH * WW;
  *(float4*)(ob + pp) = make_float4(ro[0], ro[1], ro[2], ro[3]);
  *(float4*)(ob + HH * WW + pp) = make_float4(go[0], go[1], go[2], go[3]);
  *(float4*)(ob + 2 * HH * WW + pp) = make_float4(bo[0], bo[1], bo[2], bo[3]);
}

extern "C" void kernel_launch(void* const* d_in, const int* in_sizes, int n_in,
                              void* d_out, int out_size, void* d_ws, size_t ws_size,
                              hipStream_t stream) {
  const float* image = (const float*)d_in[0];
  const float* val   = (const float*)d_in[1];
  const float* sw0 = (const float*)d_in[2];  const float* sb0 = (const float*)d_in[3];
  const float* sw1 = (const float*)d_in[4];  const float* sb1 = (const float*)d_in[5];
  const float* sw2 = (const float*)d_in[6];  const float* sb2 = (const float*)d_in[7];
  const float* sw3 = (const float*)d_in[8];  const float* sb3 = (const float*)d_in[9];
  const float* spw = (const float*)d_in[10]; const float* spb = (const float*)d_in[11];
  const float* lw1 = (const float*)d_in[12]; const float* lb1 = (const float*)d_in[13];
  const float* lw2 = (const float*)d_in[14]; const float* lb2 = (const float*)d_in[15];
  const float* lw3 = (const float*)d_in[16]; const float* lb3 = (const float*)d_in[17];
  const float* cw  = (const float*)d_in[18]; const float* cb  = (const float*)d_in[19];
  const float* fw1 = (const float*)d_in[20]; const float* fb1 = (const float*)d_in[21];
  const float* fw2 = (const float*)d_in[22]; const float* fb2 = (const float*)d_in[23];
  const float* gw  = (const float*)d_in[24]; const float* gb  = (const float*)d_in[25];
  const float* ccm_w = (const float*)d_in[26]; const float* ccm_b = (const float*)d_in[27];
  const float* shifts = (const float*)d_in[28]; const float* slopes = (const float*)d_in[29];
  const float* prw = (const float*)d_in[30]; const float* prb = (const float*)d_in[31];
  float* out = (float*)d_out;

  float* ws    = (float*)d_ws;
  float* low   = ws;                  // 786432
  float* x0    = low + 786432;        // 524288
  float* x1    = x0 + 524288;         // 262144
  float* x2    = x1 + 262144;         // 131072
  float* x3    = x2 + 131072;         // 65536
  float* splat = x3 + 65536;          // 65536
  float* loc1  = splat + 65536;       // 131072
  float* loc2  = loc1 + 131072;       // 131072
  float* loc3  = loc2 + 131072;       // 65536
  float* fc2o  = loc3 + 65536;        // 256
  float* gridt = fc2o + 256;          // 98304

  downsample_k<<<3072, 256, 0, stream>>>(image, low);
  conv_s2_k<3, 8, 256><<<2048, 256, 0, stream>>>(low, sw0, sb0, x0);
  conv_s2_k<8, 16, 128><<<1024, 256, 0, stream>>>(x0, sw1, sb1, x1);
  conv_s2_k<16, 32, 64><<<512, 256, 0, stream>>>(x1, sw2, sb2, x2);
  conv_s2_k<32, 64, 32><<<256, 256, 0, stream>>>(x2, sw3, sb3, x3);
  splat_k<<<256, 256, 0, stream>>>(x3, spw, spb, val, splat);
  pw_relu_k<64, 128><<<512, 256, 0, stream>>>(splat, lw1, lb1, loc1);
  pw_relu_k<128, 128><<<512, 256, 0, stream>>>(loc1, lw2, lb2, loc2);
  pw_relu_k<128, 64><<<256, 256, 0, stream>>>(loc2, lw3, lb3, loc3);
  cpfc_k<<<1, 256, 0, stream>>>(splat, cw, cb, fw1, fb1, fw2, fb2, fc2o);
  coeff_k<<<384, 256, 0, stream>>>(loc3, fc2o, gw, gb, gridt);
  slice_k<<<4096, 256, 0, stream>>>(image, gridt, ccm_w, ccm_b, shifts, slopes,
                                    prw, prb, out);
}

// Round 4
// 332.985 us; speedup vs baseline: 1.3072x; 1.0184x over previous
//
#include <hip/hip_runtime.h>

#define BATCH 4
#define HH 1024
#define WW 1024

// ---------------- fused downsample(1024->256) + conv0 (3->8, s2, relu) -------
// One block per (b, 16x16 output tile). Low-res support = 33x33x3 staged in LDS,
// computed on the fly from the image (avg of 2x2 pixels at 4g+1,4g+2).
__global__ __launch_bounds__(256) void dsconv0_k(const float* __restrict__ img,
                                                 const float* __restrict__ wgt,
                                                 const float* __restrict__ bias,
                                                 float* __restrict__ out) {
  int blk = blockIdx.x;            // b*64 + ty*8 + tx
  int tx = blk & 7;
  int ty = (blk >> 3) & 7;
  int b = blk >> 6;
  int t = threadIdx.x;

  __shared__ float low[3][33][36];  // padded row stride 36

  int Y0 = ty << 4, X0 = tx << 4;  // output tile origin (128x128 space)
  int gy0 = 2 * Y0 - 1, gx0 = 2 * X0 - 1;  // low-res support origin

  for (int i = t; i < 3 * 33 * 33; i += 256) {
    int c = i / 1089;
    int rem = i - c * 1089;
    int ly = rem / 33;
    int lx = rem - ly * 33;
    int gy = gy0 + ly, gx = gx0 + lx;
    float v = 0.f;
    if (gy >= 0 && gx >= 0) {  // gy,gx <= 255 by construction
      const float* p = img + (size_t)(b * 3 + c) * HH * WW + (4 * gy + 1) * WW + 4 * gx + 1;
      v = 0.25f * (p[0] + p[1] + p[WW] + p[WW + 1]);
    }
    low[c][ly][lx] = v;
  }
  __syncthreads();

  int x = t & 15, y = t >> 4;  // local output coords
  float acc[8];
#pragma unroll
  for (int o = 0; o < 8; ++o) acc[o] = bias[o];
  for (int ci = 0; ci < 3; ++ci) {
#pragma unroll
    for (int ky = 0; ky < 3; ++ky) {
#pragma unroll
      for (int kx = 0; kx < 3; ++kx) {
        float v = low[ci][2 * y + ky][2 * x + kx];
#pragma unroll
        for (int o = 0; o < 8; ++o)
          acc[o] += wgt[o * 27 + ci * 9 + ky * 3 + kx] * v;
      }
    }
  }
  float* ob = out + (size_t)b * 8 * 128 * 128 + (Y0 + y) * 128 + X0 + x;
#pragma unroll
  for (int o = 0; o < 8; ++o) ob[o * 128 * 128] = fmaxf(acc[o], 0.f);
}

// ---------------- 3x3 stride-2 conv, pad 1, relu ------------------------------
template <int CI, int CO, int HI>
__global__ __launch_bounds__(256) void conv_s2_k(const float* __restrict__ in,
                                                 const float* __restrict__ wgt,
                                                 const float* __restrict__ bias,
                                                 float* __restrict__ out) {
  const int WI = HI;
  const int HO = HI / 2, WO = HI / 2;
  int idx = blockIdx.x * 256 + threadIdx.x;
  if (idx >= BATCH * CO * HO * WO) return;
  int x = idx % WO;
  int t = idx / WO;
  int y = t % HO; t /= HO;
  int o = t % CO;
  int b = t / CO;
  float acc = bias[o];
  int iy0 = 2 * y - 1, ix0 = 2 * x - 1;
  for (int ci = 0; ci < CI; ++ci) {
    const float* ip = in + (size_t)(b * CI + ci) * HI * WI;
    const float* wp = wgt + (o * CI + ci) * 9;
#pragma unroll
    for (int ky = 0; ky < 3; ++ky) {
      int iy = iy0 + ky;
      if (iy < 0 || iy >= HI) continue;
#pragma unroll
      for (int kx = 0; kx < 3; ++kx) {
        int ix = ix0 + kx;
        if (ix < 0 || ix >= WI) continue;
        acc += wp[ky * 3 + kx] * ip[iy * WI + ix];
      }
    }
  }
  out[idx] = fmaxf(acc, 0.0f);
}

// ---------------- splat = pw(x3, spw) + spb + val  (NO relu) ------------------
__global__ __launch_bounds__(256) void splat_k(const float* __restrict__ x3,
                                               const float* __restrict__ spw,
                                               const float* __restrict__ spb,
                                               const float* __restrict__ val,
                                               float* __restrict__ out) {
  int idx = blockIdx.x * 256 + threadIdx.x;  // B*64*256 = 65536
  int p = idx & 255;
  int o = (idx >> 8) & 63;
  int b = idx >> 14;
  float acc = spb[o] + val[b];
  const float* w = spw + o * 64;
  const float* xb = x3 + ((size_t)b * 64) * 256 + p;
#pragma unroll 8
  for (int c = 0; c < 64; ++c) acc += w[c] * xb[c * 256];
  out[idx] = acc;
}

// ---------------- pointwise conv + relu ---------------------------------------
template <int CI, int CO>
__global__ __launch_bounds__(256) void pw_relu_k(const float* __restrict__ in,
                                                 const float* __restrict__ wgt,
                                                 const float* __restrict__ bias,
                                                 float* __restrict__ out) {
  int idx = blockIdx.x * 256 + threadIdx.x;
  if (idx >= BATCH * CO * 256) return;
  int p = idx & 255;
  int o = (idx >> 8) % CO;
  int b = idx / (CO * 256);
  float acc = bias[o];
  const float* w = wgt + o * CI;
  const float* xb = in + ((size_t)b * CI) * 256 + p;
#pragma unroll 8
  for (int c = 0; c < CI; ++c) acc += w[c] * xb[c * 256];
  out[idx] = fmaxf(acc, 0.0f);
}

// ---------------- fused global path: cpool + 2 FC layers (one block) ----------
__global__ __launch_bounds__(256) void cpfc_k(const float* __restrict__ splat,
                                              const float* __restrict__ cw,
                                              const float* __restrict__ cb,
                                              const float* __restrict__ fw1,
                                              const float* __restrict__ fb1,
                                              const float* __restrict__ fw2,
                                              const float* __restrict__ fb2,
                                              float* __restrict__ fc2o) {
  __shared__ float sc[256];
  __shared__ float h1[256];
  int t = threadIdx.x;
  int b = t >> 6;
  int r = t & 63;                 // ch*16 + py*4 + px
  int ch = r >> 4;
  int py = (r >> 2) & 3;
  int px = r & 3;
  float sum = 0.f;
  for (int dy = 0; dy < 2; ++dy)
    for (int dx = 0; dx < 2; ++dx) {
      int yy = py * 2 + dy, xx = px * 2 + dx;  // position in 8x8
      int p = (yy * 2) * 16 + xx * 2;          // ::2,::2 of 16x16
      float acc = cb[ch];
      const float* w = cw + ch * 64;
      const float* xb = splat + ((size_t)b * 64) * 256 + p;
#pragma unroll 8
      for (int c = 0; c < 64; ++c) acc += w[c] * xb[c * 256];
      sum += fmaxf(acc, 0.f);
    }
  sc[t] = sum * 0.25f;
  __syncthreads();
  int o = t & 63;
  float acc = fb1[o];
#pragma unroll 8
  for (int k = 0; k < 64; ++k) acc += fw1[o * 64 + k] * sc[b * 64 + k];
  h1[t] = fmaxf(acc, 0.f);
  __syncthreads();
  acc = fb2[o];
#pragma unroll 8
  for (int k = 0; k < 64; ++k) acc += fw2[o * 64 + k] * h1[b * 64 + k];
  fc2o[t] = fmaxf(acc, 0.f);
}

// ---------------- fused = relu(loc3 + c), coeff = pw(fused, gw), scatter grid -
// grid_t layout: [b][z(8)][gy*16+gx][cc(12)]  (cc contiguous -> float4-able)
__global__ __launch_bounds__(256) void coeff_k(const float* __restrict__ loc3,
                                               const float* __restrict__ fc2o,
                                               const float* __restrict__ gw,
                                               const float* __restrict__ gb,
                                               float* __restrict__ gridt) {
  int idx = blockIdx.x * 256 + threadIdx.x;  // B*96*256 = 98304
  int p = idx & 255;
  int o = (idx >> 8) % 96;
  int b = idx / (96 * 256);
  float acc = gb[o];
  const float* w = gw + o * 64;
  const float* xb = loc3 + ((size_t)b * 64) * 256 + p;
  const float* cvb = fc2o + b * 64;
#pragma unroll 8
  for (int c = 0; c < 64; ++c) {
    float f = xb[c * 256] + cvb[c];
    acc += w[c] * fmaxf(f, 0.f);
  }
  int l = o / 12, cc = o % 12;
  gridt[(size_t)(((b * 8 + l) << 8) + p) * 12 + cc] = acc;
}

// ---------------- guide + bilateral slice + affine apply (fused, LDS grid) ----
// One block per (batch, image row). wy is uniform per block, so the y-lerp is
// folded into the staging phase: LDS holds the y-interpolated grid,
// g_y[z][x][c], 8 z-slabs x 16 x x 12 coeffs. Per-pixel trilerp is then 2D
// (z,x): 4 corners x 12 fma instead of 8 x 12.
// Slab stride 200 floats (16B aligned; 200%32=8 -> adjacent z shifted 8 banks).
#define ZST 200
__global__ __launch_bounds__(256) void slice_k(
    const float* __restrict__ img, const float* __restrict__ gridt,
    const float* __restrict__ ccm_w, const float* __restrict__ ccm_b,
    const float* __restrict__ shifts, const float* __restrict__ slopes,
    const float* __restrict__ prw, const float* __restrict__ prb,
    float* __restrict__ out) {
  int blk = blockIdx.x;          // BATCH*1024
  int b = blk >> 10;
  int h = blk & 1023;
  int t = threadIdx.x;

  __shared__ float sg[8 * ZST];  // 6400 B

  float cy = (h + 0.5f) * 0.015625f - 0.5f;
  float y0f = floorf(cy);
  float wy = cy - y0f;
  int y0 = (int)y0f;
  int yi0 = min(max(y0, 0), 15), yi1 = min(max(y0 + 1, 0), 15);

  // stage y-lerped grid: 8 slabs x 48 float4 (192 floats contiguous in global)
  for (int i = t; i < 384; i += 256) {
    int z = i / 48;
    int e = i - z * 48;
    const float4* s0 =
        (const float4*)(gridt + (size_t)(((b * 8 + z) << 8) + (yi0 << 4)) * 12);
    const float4* s1 =
        (const float4*)(gridt + (size_t)(((b * 8 + z) << 8) + (yi1 << 4)) * 12);
    float4 a = s0[e], c = s1[e];
    float4 v = make_float4(a.x + wy * (c.x - a.x), a.y + wy * (c.y - a.y),
                           a.z + wy * (c.z - a.z), a.w + wy * (c.w - a.w));
    *((float4*)(sg + z * ZST) + e) = v;
  }
  __syncthreads();

  int pp = (h << 10) + (t << 2);  // offset within one plane
  const float* ib = img + (size_t)b * 3 * HH * WW;
  float4 R4 = *(const float4*)(ib + pp);
  float4 G4 = *(const float4*)(ib + HH * WW + pp);
  float4 B4 = *(const float4*)(ib + 2 * HH * WW + pp);
  float r_[4] = {R4.x, R4.y, R4.z, R4.w};
  float g_[4] = {G4.x, G4.y, G4.z, G4.w};
  float b_[4] = {B4.x, B4.y, B4.z, B4.w};

  float m0 = ccm_w[0], m1 = ccm_w[1], m2 = ccm_w[2];
  float m3 = ccm_w[3], m4 = ccm_w[4], m5 = ccm_w[5];
  float m6 = ccm_w[6], m7 = ccm_w[7], m8 = ccm_w[8];
  float c0 = ccm_b[0], c1 = ccm_b[1], c2 = ccm_b[2];
  float p0 = prw[0], p1 = prw[1], p2 = prw[2], pb = prb[0];

  float ro[4], go[4], bo[4];
#pragma unroll
  for (int j = 0; j < 4; ++j) {
    float r = r_[j], g = g_[j], bl = b_[j];
    // guide: ccm -> piecewise-linear curve -> projection -> clip
    float v0 = c0 + m0 * r + m1 * g + m2 * bl;
    float v1 = c1 + m3 * r + m4 * g + m5 * bl;
    float v2 = c2 + m6 * r + m7 * g + m8 * bl;
    float t0 = 0.f, t1 = 0.f, t2 = 0.f;
#pragma unroll
    for (int k = 0; k < 16; ++k) {
      t0 += slopes[k] * fmaxf(v0 - shifts[k], 0.f);
      t1 += slopes[16 + k] * fmaxf(v1 - shifts[16 + k], 0.f);
      t2 += slopes[32 + k] * fmaxf(v2 - shifts[32 + k], 0.f);
    }
    float gg = pb + p0 * t0 + p1 * t1 + p2 * t2;
    float guide = fminf(fmaxf(gg, 0.f), 1.f);

    int w = (t << 2) + j;
    float cx = (w + 0.5f) * 0.015625f - 0.5f;
    float x0f = floorf(cx);
    float wx = cx - x0f;
    int x0i = (int)x0f;
    int xi0 = min(max(x0i, 0), 15), xi1 = min(max(x0i + 1, 0), 15);

    float cz = guide * 8.0f - 0.5f;
    float z0f = floorf(cz);
    float wz = cz - z0f;
    int z0i = (int)z0f;
    int zi0 = min(max(z0i, 0), 7), zi1 = min(max(z0i + 1, 0), 7);

    int oz0 = zi0 * ZST, oz1 = zi1 * ZST;
    int ox0 = xi0 * 12, ox1 = xi1 * 12;
    float wz1 = wz, wz0 = 1.f - wz;
    float wx1 = wx, wx0 = 1.f - wx;

    float acc[12];
#pragma unroll
    for (int k = 0; k < 12; ++k) acc[k] = 0.f;

#pragma unroll
    for (int dz = 0; dz < 2; ++dz) {
      int oz = dz ? oz1 : oz0;
      float wzz = dz ? wz1 : wz0;
#pragma unroll
      for (int dx = 0; dx < 2; ++dx) {
        int ox = dx ? ox1 : ox0;
        float wgt = wzz * (dx ? wx1 : wx0);
        const float* gp = sg + oz + ox;
        float4 a0 = *(const float4*)gp;
        float4 a1 = *(const float4*)(gp + 4);
        float4 a2 = *(const float4*)(gp + 8);
        acc[0] += wgt * a0.x;  acc[1] += wgt * a0.y;
        acc[2] += wgt * a0.z;  acc[3] += wgt * a0.w;
        acc[4] += wgt * a1.x;  acc[5] += wgt * a1.y;
        acc[6] += wgt * a1.z;  acc[7] += wgt * a1.w;
        acc[8] += wgt * a2.x;  acc[9] += wgt * a2.y;
        acc[10] += wgt * a2.z; acc[11] += wgt * a2.w;
      }
    }
    ro[j] = acc[0] * r + acc[1] * g + acc[2] * bl + acc[3];
    go[j] = acc[4] * r + acc[5] * g + acc[6] * bl + acc[7];
    bo[j] = acc[8] * r + acc[9] * g + acc[10] * bl + acc[11];
  }
  float* ob = out + (size_t)b * 3 * HH * WW;
  *(float4*)(ob + pp) = make_float4(ro[0], ro[1], ro[2], ro[3]);
  *(float4*)(ob + HH * WW + pp) = make_float4(go[0], go[1], go[2], go[3]);
  *(float4*)(ob + 2 * HH * WW + pp) = make_float4(bo[0], bo[1], bo[2], bo[3]);
}

extern "C" void kernel_launch(void* const* d_in, const int* in_sizes, int n_in,
                              void* d_out, int out_size, void* d_ws, size_t ws_size,
                              hipStream_t stream) {
  const float* image = (const float*)d_in[0];
  const float* val   = (const float*)d_in[1];
  const float* sw0 = (const float*)d_in[2];  const float* sb0 = (const float*)d_in[3];
  const float* sw1 = (const float*)d_in[4];  const float* sb1 = (const float*)d_in[5];
  const float* sw2 = (const float*)d_in[6];  const float* sb2 = (const float*)d_in[7];
  const float* sw3 = (const float*)d_in[8];  const float* sb3 = (const float*)d_in[9];
  const float* spw = (const float*)d_in[10]; const float* spb = (const float*)d_in[11];
  const float* lw1 = (const float*)d_in[12]; const float* lb1 = (const float*)d_in[13];
  const float* lw2 = (const float*)d_in[14]; const float* lb2 = (const float*)d_in[15];
  const float* lw3 = (const float*)d_in[16]; const float* lb3 = (const float*)d_in[17];
  const float* cw  = (const float*)d_in[18]; const float* cb  = (const float*)d_in[19];
  const float* fw1 = (const float*)d_in[20]; const float* fb1 = (const float*)d_in[21];
  const float* fw2 = (const float*)d_in[22]; const float* fb2 = (const float*)d_in[23];
  const float* gw  = (const float*)d_in[24]; const float* gb  = (const float*)d_in[25];
  const float* ccm_w = (const float*)d_in[26]; const float* ccm_b = (const float*)d_in[27];
  const float* shifts = (const float*)d_in[28]; const float* slopes = (const float*)d_in[29];
  const float* prw = (const float*)d_in[30]; const float* prb = (const float*)d_in[31];
  float* out = (float*)d_out;

  float* ws    = (float*)d_ws;
  float* x0    = ws;                  // 524288
  float* x1    = x0 + 524288;         // 262144
  float* x2    = x1 + 262144;         // 131072
  float* x3    = x2 + 131072;         // 65536
  float* splat = x3 + 65536;          // 65536
  float* loc1  = splat + 65536;       // 131072
  float* loc2  = loc1 + 131072;       // 131072
  float* loc3  = loc2 + 131072;       // 65536
  float* fc2o  = loc3 + 65536;        // 256
  float* gridt = fc2o + 256;          // 98304

  dsconv0_k<<<256, 256, 0, stream>>>(image, sw0, sb0, x0);
  conv_s2_k<8, 16, 128><<<1024, 256, 0, stream>>>(x0, sw1, sb1, x1);
  conv_s2_k<16, 32, 64><<<512, 256, 0, stream>>>(x1, sw2, sb2, x2);
  conv_s2_k<32, 64, 32><<<256, 256, 0, stream>>>(x2, sw3, sb3, x3);
  splat_k<<<256, 256, 0, stream>>>(x3, spw, spb, val, splat);
  pw_relu_k<64, 128><<<512, 256, 0, stream>>>(splat, lw1, lb1, loc1);
  pw_relu_k<128, 128><<<512, 256, 0, stream>>>(loc1, lw2, lb2, loc2);
  pw_relu_k<128, 64><<<256, 256, 0, stream>>>(loc2, lw3, lb3, loc3);
  cpfc_k<<<1, 256, 0, stream>>>(splat, cw, cb, fw1, fb1, fw2, fb2, fc2o);
  coeff_k<<<384, 256, 0, stream>>>(loc3, fc2o, gw, gb, gridt);
  slice_k<<<4096, 256, 0, stream>>>(image, gridt, ccm_w, ccm_b, shifts, slopes,
                                    prw, prb, out);
}